// Round 6
// baseline (437.083 us; speedup 1.0000x reference)
//
#include <hip/hip_runtime.h>
#include <hip/hip_bf16.h>
#include <math.h>

typedef __bf16 bf16x2 __attribute__((ext_vector_type(2)));
typedef __bf16 bf16x4 __attribute__((ext_vector_type(4)));
typedef __bf16 bf16x8 __attribute__((ext_vector_type(8)));
typedef float f32x4 __attribute__((ext_vector_type(4)));
typedef float f32x16 __attribute__((ext_vector_type(16)));

#define MFMA16(a, b, c) __builtin_amdgcn_mfma_f32_16x16x32_bf16(a, b, c, 0, 0, 0)
#define MFMA32(a, b, c) __builtin_amdgcn_mfma_f32_32x32x16_bf16(a, b, c, 0, 0, 0)
#define QSCALE 0.1803368801111204f  // 0.125 * log2(e): folded into W's Q-columns

// async global->LDS, 16B/lane, dest = wave-uniform base + lane*16
__device__ __forceinline__ void gload_lds16(const __bf16* g, __bf16* l) {
  __builtin_amdgcn_global_load_lds((const __attribute__((address_space(1))) void*)g,
                                   (__attribute__((address_space(3))) void*)l,
                                   16, 0, 0);
}

// ---------------------------------------------------------------------------
// Kernel 0: convert X fp32 -> bf16
// ---------------------------------------------------------------------------
__global__ __launch_bounds__(256) void convert_x(const float* __restrict__ in,
                                                 __bf16* __restrict__ out) {
  int i = blockIdx.x * 256 + threadIdx.x;
  float4 v = ((const float4*)in)[i];
  bf16x4 o = {(__bf16)v.x, (__bf16)v.y, (__bf16)v.z, (__bf16)v.w};
  *(bf16x4*)&out[i * 4] = o;
}

// ---------------------------------------------------------------------------
// Kernel 1: transpose+convert W fp32 [1024,3072] -> Wt bf16 [3072,1024].
//   Q output-features (bx<16) pre-scaled by 0.125*log2(e).
// ---------------------------------------------------------------------------
__global__ __launch_bounds__(256) void transpose_w(const float* __restrict__ W,
                                                   __bf16* __restrict__ Wt) {
  __shared__ __bf16 tile[64][65];
  const int bx = blockIdx.x;
  const int by = blockIdx.y;
  const int t = threadIdx.x;
  const int lr = t >> 6;
  const int lc = t & 63;
  const float sc = (bx < 16) ? QSCALE : 1.0f;  // block-uniform
#pragma unroll
  for (int i = 0; i < 16; ++i) {
    int r = lr + i * 4;
    tile[r][lc] = (__bf16)(W[(size_t)(by * 64 + r) * 3072 + bx * 64 + lc] * sc);
  }
  __syncthreads();
#pragma unroll
  for (int i = 0; i < 16; ++i) {
    int r = lr + i * 4;
    Wt[(size_t)(bx * 64 + r) * 1024 + by * 64 + lc] = tile[lc][r];
  }
}

// ---------------------------------------------------------------------------
// Kernel 2: QKV = X @ W. 128x128 tile, BK=32, global_load_lds width=16.
//   Q,K columns (n<2048) -> QK [8192,2048] row-major.
//   V columns (n>=2048)  -> Vt [b*16+h][d=64][key=2048] directly (fused
//   transpose: C-layout gives 4 consecutive keys per reg -> bf16x4 stores).
// ---------------------------------------------------------------------------
__global__ __launch_bounds__(256) void gemm_qkv(const __bf16* __restrict__ X,
                                                const __bf16* __restrict__ Wt,
                                                __bf16* __restrict__ QK,
                                                __bf16* __restrict__ Vt) {
  __shared__ __bf16 As[128 * 32];
  __shared__ __bf16 Bs[128 * 32];
  const int t = threadIdx.x;
  const int lane = t & 63;
  const int wave = t >> 6;
  const int quad = lane >> 4;
  const int l16 = lane & 15;
  const int n0 = blockIdx.x * 128;
  const int m0 = blockIdx.y * 128;
  const int wm = (wave & 1) * 64;
  const int wn = (wave >> 1) * 64;

  const __bf16* Ag = &X[(size_t)(m0 + wave * 16 + (lane >> 2)) * 1024 + (lane & 3) * 8];
  const __bf16* Bg = &Wt[(size_t)(n0 + wave * 16 + (lane >> 2)) * 1024 + (lane & 3) * 8];
  __bf16* As0 = &As[wave * 512];
  __bf16* As1 = &As[2048 + wave * 512];
  __bf16* Bs0 = &Bs[wave * 512];
  __bf16* Bs1 = &Bs[2048 + wave * 512];

  f32x4 acc[4][4] = {};

  for (int k0 = 0; k0 < 1024; k0 += 32) {
    gload_lds16(Ag + k0, As0);
    gload_lds16(Ag + (size_t)64 * 1024 + k0, As1);
    gload_lds16(Bg + k0, Bs0);
    gload_lds16(Bg + (size_t)64 * 1024 + k0, Bs1);
    __syncthreads();

    bf16x8 af[4], bf[4];
#pragma unroll
    for (int mi = 0; mi < 4; ++mi)
      af[mi] = *(const bf16x8*)&As[(wm + mi * 16 + l16) * 32 + quad * 8];
#pragma unroll
    for (int ni = 0; ni < 4; ++ni)
      bf[ni] = *(const bf16x8*)&Bs[(wn + ni * 16 + l16) * 32 + quad * 8];
#pragma unroll
    for (int mi = 0; mi < 4; ++mi)
#pragma unroll
      for (int ni = 0; ni < 4; ++ni)
        acc[mi][ni] = MFMA16(af[mi], bf[ni], acc[mi][ni]);
    __syncthreads();
  }

  if (n0 < 2048) {
    // Q/K epilogue: row-major QK, stride 2048
#pragma unroll
    for (int mi = 0; mi < 4; ++mi)
#pragma unroll
      for (int ni = 0; ni < 4; ++ni)
#pragma unroll
        for (int r = 0; r < 4; ++r) {
          int row = m0 + wm + mi * 16 + quad * 4 + r;
          int col = n0 + wn + ni * 16 + l16;
          QK[(size_t)row * 2048 + col] = (__bf16)acc[mi][ni][r];
        }
  } else {
    // V epilogue: fused transpose into Vt[bh][d][key]; 4 consecutive keys
#pragma unroll
    for (int mi = 0; mi < 4; ++mi)
#pragma unroll
      for (int ni = 0; ni < 4; ++ni) {
        int v = n0 + wn + ni * 16 + l16 - 2048;
        int hh = v >> 6, d = v & 63;
        int row0 = m0 + wm + mi * 16 + quad * 4;
        int bb = row0 >> 11, key = row0 & 2047;
        bf16x4 pk = {(__bf16)acc[mi][ni][0], (__bf16)acc[mi][ni][1],
                     (__bf16)acc[mi][ni][2], (__bf16)acc[mi][ni][3]};
        *(bf16x4*)&Vt[((size_t)(bb * 16 + hh) * 64 + d) * 2048 + key] = pk;
      }
  }
}

// ---------------------------------------------------------------------------
// Kernel 3: flash attention, 32x32x16 MFMA, ZERO-LDS / ZERO-BARRIER.
//   K,V per (b,h) are 256 KB each -> L2-resident (m169 regime: staging such
//   data in LDS is pure overhead). Each wave streams K/V fragments DIRECTLY
//   from global: the 4 waves of a block read identical lines (L1/L2-served;
//   each 128B line fully consumed by the dc/kk x half fragment loops), and
//   with no barriers waves are fully independent -> no lockstep tax, and the
//   compiler is free to pipeline next-round loads across iterations.
//   The old staged-K row permutation (bits 2<->3) becomes a free index
//   computation on the lane: krow = swap23(l31). exp2 outputs land directly
//   in PV A-frag order (no shuffles). Fixed-max softmax; denominator =
//   per-lane sum + one shfl_xor(32) (halves partition keys).
// ---------------------------------------------------------------------------
__global__ __launch_bounds__(256) void attn(const __bf16* __restrict__ QK,
                                            const __bf16* __restrict__ Vt,
                                            float* __restrict__ Out) {
  const int h = blockIdx.y;
  const int b = blockIdx.z;
  const int t = threadIdx.x;
  const int lane = t & 63;
  const int wave = t >> 6;
  const int l31 = lane & 31;
  const int half = lane >> 5;
  const int q0w = blockIdx.x * 128 + wave * 32;

  const size_t base = (size_t)b * 2048 * 2048;
  const __bf16* Qb = QK + base + h * 64;
  const __bf16* Kb = QK + base + 1024 + h * 64;
  const __bf16* Vtb = Vt + (size_t)(b * 16 + h) * 64 * 2048;  // [d][key]

  // Q as B-operand: lane holds Q[q0w+l31][dc*16 + half*8 + j]  (pre-scaled)
  bf16x8 qf[4];
#pragma unroll
  for (int dc = 0; dc < 4; ++dc)
    qf[dc] = *(const bf16x8*)&Qb[(size_t)(q0w + l31) * 2048 + dc * 16 + half * 8];

  f32x16 o[2] = {};
  f32x4 ls = {0.0f, 0.0f, 0.0f, 0.0f};

  // permuted K row for this lane: swap bits 2<->3 of l31 (involution).
  // (Was the staged-LDS row permutation; now just lane-local index math.)
  const int krow = (l31 & ~12) | ((l31 & 4) << 1) | ((l31 & 8) >> 1);

  const __bf16* Kl = &Kb[(size_t)krow * 2048];            // + kv0*2048 + kt*32*2048
  const __bf16* Vl = &Vtb[(size_t)l31 * 2048];            // + dt*32*2048 + kv0

  for (int kv0 = 0; kv0 < 2048; kv0 += 64) {
    // ---- S^T = K.Q^T per 32-key tile; exp2 directly into A-frag order ----
    bf16x8 pf[4];
#pragma unroll
    for (int kt = 0; kt < 2; ++kt) {
      f32x16 c = {};
#pragma unroll
      for (int dc = 0; dc < 4; ++dc) {
        bf16x8 kf = *(const bf16x8*)&Kl[(size_t)(kv0 + kt * 32) * 2048 +
                                        dc * 16 + half * 8];
        c = MFMA32(kf, qf[dc], c);
      }
#pragma unroll
      for (int kkl = 0; kkl < 2; ++kkl) {
        bf16x8 f;
#pragma unroll
        for (int j = 0; j < 8; ++j) {
          float e = __builtin_amdgcn_exp2f(c[8 * kkl + 4 * (j >> 2) + (j & 3)]);
          ls[j & 3] += e;
          f[j] = (__bf16)e;
        }
        pf[kt * 2 + kkl] = f;
      }
    }

    // ---- O += P V (V fragments straight from L2) ----
#pragma unroll
    for (int dt = 0; dt < 2; ++dt)
#pragma unroll
      for (int kk = 0; kk < 4; ++kk) {
        bf16x8 vf = *(const bf16x8*)&Vl[(size_t)dt * 32 * 2048 + kv0 +
                                        kk * 16 + half * 8];
        o[dt] = MFMA32(pf[kk], vf, o[dt]);
      }
  }

  // ---- denominator: the two halves partition each q's keys ----
  float lsum = (ls[0] + ls[1]) + (ls[2] + ls[3]);
  lsum += __shfl_xor(lsum, 32);
  float inv = 1.0f / lsum;  // valid for q == l31

  float iv[16];
#pragma unroll
  for (int r = 0; r < 16; ++r)
    iv[r] = __shfl(inv, (r & 3) + 8 * (r >> 2) + 4 * half);

  // ---- epilogue: O C-layout col=l31=d(+32dt), row=q regmap ----
#pragma unroll
  for (int dt = 0; dt < 2; ++dt)
#pragma unroll
    for (int r = 0; r < 16; ++r) {
      int qr = (r & 3) + 8 * (r >> 2) + 4 * half;
      Out[(size_t)(b * 2048 + q0w + qr) * 1024 + h * 64 + dt * 32 + l31] =
          o[dt][r] * iv[r];
    }
}

// ---------------------------------------------------------------------------
extern "C" void kernel_launch(void* const* d_in, const int* in_sizes, int n_in,
                              void* d_out, int out_size, void* d_ws, size_t ws_size,
                              hipStream_t stream) {
  const float* x = (const float*)d_in[0];        // [4,2048,1024] fp32
  const float* w = (const float*)d_in[1];        // [1024,3072]  fp32
  float* out = (float*)d_out;                    // [4,2048,1024] fp32

  __bf16* Wt = (__bf16*)d_ws;                    // [3072,1024]   6.29 MB
  __bf16* QK = Wt + (size_t)3072 * 1024;         // [8192,2048]  33.55 MB
  __bf16* Xb = QK + (size_t)8192 * 2048;         // [8192,1024]  16.78 MB
  __bf16* Vtr = Xb + (size_t)8192 * 1024;        // [64,64,2048] 16.78 MB

  convert_x<<<8192, 256, 0, stream>>>(x, Xb);
  transpose_w<<<dim3(48, 16), 256, 0, stream>>>(w, Wt);
  gemm_qkv<<<dim3(24, 64), 256, 0, stream>>>(Xb, Wt, QK, Vtr);
  attn<<<dim3(16, 16, 4), 256, 0, stream>>>(QK, Vtr, out);
}

// Round 8
// 234.317 us; speedup vs baseline: 1.8653x; 1.8653x over previous
//
#include <hip/hip_runtime.h>
#include <hip/hip_bf16.h>
#include <math.h>

typedef __bf16 bf16x2 __attribute__((ext_vector_type(2)));
typedef __bf16 bf16x4 __attribute__((ext_vector_type(4)));
typedef __bf16 bf16x8 __attribute__((ext_vector_type(8)));
typedef float f32x4 __attribute__((ext_vector_type(4)));
typedef float f32x16 __attribute__((ext_vector_type(16)));

#define MFMA16(a, b, c) __builtin_amdgcn_mfma_f32_16x16x32_bf16(a, b, c, 0, 0, 0)
#define MFMA32(a, b, c) __builtin_amdgcn_mfma_f32_32x32x16_bf16(a, b, c, 0, 0, 0)
#define QSCALE 0.1803368801111204f  // 0.125 * log2(e): folded into W's Q-columns

// async global->LDS, 16B/lane, dest = wave-uniform base + lane*16
__device__ __forceinline__ void gload_lds16(const __bf16* g, __bf16* l) {
  __builtin_amdgcn_global_load_lds((const __attribute__((address_space(1))) void*)g,
                                   (__attribute__((address_space(3))) void*)l,
                                   16, 0, 0);
}

// ---------------------------------------------------------------------------
// Kernel 0: convert X fp32 -> bf16
// ---------------------------------------------------------------------------
__global__ __launch_bounds__(256) void convert_x(const float* __restrict__ in,
                                                 __bf16* __restrict__ out) {
  int i = blockIdx.x * 256 + threadIdx.x;
  float4 v = ((const float4*)in)[i];
  bf16x4 o = {(__bf16)v.x, (__bf16)v.y, (__bf16)v.z, (__bf16)v.w};
  *(bf16x4*)&out[i * 4] = o;
}

// ---------------------------------------------------------------------------
// Kernel 1: transpose+convert W fp32 [1024,3072] -> Wt bf16 [3072,1024].
//   Q output-features (bx<16) pre-scaled by 0.125*log2(e).
// ---------------------------------------------------------------------------
__global__ __launch_bounds__(256) void transpose_w(const float* __restrict__ W,
                                                   __bf16* __restrict__ Wt) {
  __shared__ __bf16 tile[64][65];
  const int bx = blockIdx.x;
  const int by = blockIdx.y;
  const int t = threadIdx.x;
  const int lr = t >> 6;
  const int lc = t & 63;
  const float sc = (bx < 16) ? QSCALE : 1.0f;  // block-uniform
#pragma unroll
  for (int i = 0; i < 16; ++i) {
    int r = lr + i * 4;
    tile[r][lc] = (__bf16)(W[(size_t)(by * 64 + r) * 3072 + bx * 64 + lc] * sc);
  }
  __syncthreads();
#pragma unroll
  for (int i = 0; i < 16; ++i) {
    int r = lr + i * 4;
    Wt[(size_t)(bx * 64 + r) * 1024 + by * 64 + lc] = tile[lc][r];
  }
}

// ---------------------------------------------------------------------------
// Kernel 2: QKV = X @ W. 128x128 tile, BK=32, global_load_lds width=16.
//   Q,K columns (n<2048) -> QK [8192,2048] row-major.
//   V columns (n>=2048)  -> Vt [b*16+h][d=64][key=2048] directly (fused
//   transpose: C-layout gives 4 consecutive keys per reg -> bf16x4 stores).
// ---------------------------------------------------------------------------
__global__ __launch_bounds__(256) void gemm_qkv(const __bf16* __restrict__ X,
                                                const __bf16* __restrict__ Wt,
                                                __bf16* __restrict__ QK,
                                                __bf16* __restrict__ Vt) {
  __shared__ __bf16 As[128 * 32];
  __shared__ __bf16 Bs[128 * 32];
  const int t = threadIdx.x;
  const int lane = t & 63;
  const int wave = t >> 6;
  const int quad = lane >> 4;
  const int l16 = lane & 15;
  const int n0 = blockIdx.x * 128;
  const int m0 = blockIdx.y * 128;
  const int wm = (wave & 1) * 64;
  const int wn = (wave >> 1) * 64;

  const __bf16* Ag = &X[(size_t)(m0 + wave * 16 + (lane >> 2)) * 1024 + (lane & 3) * 8];
  const __bf16* Bg = &Wt[(size_t)(n0 + wave * 16 + (lane >> 2)) * 1024 + (lane & 3) * 8];
  __bf16* As0 = &As[wave * 512];
  __bf16* As1 = &As[2048 + wave * 512];
  __bf16* Bs0 = &Bs[wave * 512];
  __bf16* Bs1 = &Bs[2048 + wave * 512];

  f32x4 acc[4][4] = {};

  for (int k0 = 0; k0 < 1024; k0 += 32) {
    gload_lds16(Ag + k0, As0);
    gload_lds16(Ag + (size_t)64 * 1024 + k0, As1);
    gload_lds16(Bg + k0, Bs0);
    gload_lds16(Bg + (size_t)64 * 1024 + k0, Bs1);
    __syncthreads();

    bf16x8 af[4], bf[4];
#pragma unroll
    for (int mi = 0; mi < 4; ++mi)
      af[mi] = *(const bf16x8*)&As[(wm + mi * 16 + l16) * 32 + quad * 8];
#pragma unroll
    for (int ni = 0; ni < 4; ++ni)
      bf[ni] = *(const bf16x8*)&Bs[(wn + ni * 16 + l16) * 32 + quad * 8];
#pragma unroll
    for (int mi = 0; mi < 4; ++mi)
#pragma unroll
      for (int ni = 0; ni < 4; ++ni)
        acc[mi][ni] = MFMA16(af[mi], bf[ni], acc[mi][ni]);
    __syncthreads();
  }

  if (n0 < 2048) {
    // Q/K epilogue: row-major QK, stride 2048
#pragma unroll
    for (int mi = 0; mi < 4; ++mi)
#pragma unroll
      for (int ni = 0; ni < 4; ++ni)
#pragma unroll
        for (int r = 0; r < 4; ++r) {
          int row = m0 + wm + mi * 16 + quad * 4 + r;
          int col = n0 + wn + ni * 16 + l16;
          QK[(size_t)row * 2048 + col] = (__bf16)acc[mi][ni][r];
        }
  } else {
    // V epilogue: fused transpose into Vt[bh][d][key]; 4 consecutive keys
#pragma unroll
    for (int mi = 0; mi < 4; ++mi)
#pragma unroll
      for (int ni = 0; ni < 4; ++ni) {
        int v = n0 + wn + ni * 16 + l16 - 2048;
        int hh = v >> 6, d = v & 63;
        int row0 = m0 + wm + mi * 16 + quad * 4;
        int bb = row0 >> 11, key = row0 & 2047;
        bf16x4 pk = {(__bf16)acc[mi][ni][0], (__bf16)acc[mi][ni][1],
                     (__bf16)acc[mi][ni][2], (__bf16)acc[mi][ni][3]};
        *(bf16x4*)&Vt[((size_t)(bb * 16 + hh) * 64 + d) * 2048 + key] = pk;
      }
  }
}

// ---------------------------------------------------------------------------
// Kernel 3: flash attention, 32x32x16 MFMA, PERMUTED-K staging.
//   R1-verified structure (91.1 us): stage K[64][64] row-permuted (bits
//   2<->3) + V[64][64] per round, 2 barriers per 64 keys. exp2 outputs land
//   directly in PV A-frag order (no LDS round-trip, no shuffles). Fixed-max
//   softmax; denominator = per-lane sum + one shfl_xor(32).
//   NEW (T1): XCD-aware block remap. Default dispatch round-robins the 16
//   q-blocks of one (b,h) across 8 XCDs -> every XCD touches ~all 64 K/V
//   panels (32 MB) vs 4 MB L2 -> measured 139 MB HBM fetch (2.8x compulsory).
//   Remap flat id so each XCD owns 8 whole (b,h) panels (8x512KB = 4MB = L2):
//     flat = bx + 16*by + 256*bz ; xcd = flat&7 ; i = flat>>3
//     bh = xcd*8 + (i>>4) ; qb = i&15      (bijective: 1024 % 8 == 0)
// ---------------------------------------------------------------------------
#define AT_LD 72  // 144B rows, 16B-aligned

__global__ __launch_bounds__(256) void attn(const __bf16* __restrict__ QK,
                                            const __bf16* __restrict__ Vt,
                                            float* __restrict__ Out) {
  const int t = threadIdx.x;
  const int lane = t & 63;
  const int wave = t >> 6;
  const int l31 = lane & 31;
  const int half = lane >> 5;

  // ---- XCD-aware remap (T1) ----
  const int flat = blockIdx.x + (blockIdx.y << 4) + (blockIdx.z << 8);
  const int xcd = flat & 7;
  const int idx = flat >> 3;
  const int bh = xcd * 8 + (idx >> 4);  // 8 (b,h) panels per XCD
  const int qb = idx & 15;
  const int b = bh >> 4;
  const int h = bh & 15;
  const int q0w = qb * 128 + wave * 32;

  const size_t base = (size_t)b * 2048 * 2048;
  const __bf16* Qb = QK + base + h * 64;
  const __bf16* Kb = QK + base + 1024 + h * 64;
  const __bf16* Vtb = Vt + (size_t)(b * 16 + h) * 64 * 2048;  // [d][key]

  __shared__ __bf16 Ks[64 * AT_LD];  // [perm(key)][d]
  __shared__ __bf16 Vs[64 * AT_LD];  // [d][key]

  // Q as B-operand: lane holds Q[q0w+l31][dc*16 + half*8 + j]  (pre-scaled)
  bf16x8 qf[4];
#pragma unroll
  for (int dc = 0; dc < 4; ++dc)
    qf[dc] = *(const bf16x8*)&Qb[(size_t)(q0w + l31) * 2048 + dc * 16 + half * 8];

  f32x16 o[2] = {};
  float lsum = 0.0f;

  const int srow = t >> 2;      // staging row 0..63
  const int sc = (t & 3) * 16;  // staging col chunk
  // K dest row: swap bits 2<->3 (involution); bits 0,1,4,5 kept
  const int prow = (srow & 51) | ((srow & 4) << 1) | ((srow & 8) >> 1);

  for (int kv0 = 0; kv0 < 2048; kv0 += 64) {
    // ---- stage K (row-permuted) and V ----
    bf16x8 k0v = *(const bf16x8*)&Kb[(size_t)(kv0 + srow) * 2048 + sc];
    bf16x8 k1v = *(const bf16x8*)&Kb[(size_t)(kv0 + srow) * 2048 + sc + 8];
    bf16x8 v0v = *(const bf16x8*)&Vtb[(size_t)srow * 2048 + kv0 + sc];
    bf16x8 v1v = *(const bf16x8*)&Vtb[(size_t)srow * 2048 + kv0 + sc + 8];
    __syncthreads();
    *(bf16x8*)&Ks[prow * AT_LD + sc] = k0v;
    *(bf16x8*)&Ks[prow * AT_LD + sc + 8] = k1v;
    *(bf16x8*)&Vs[srow * AT_LD + sc] = v0v;
    *(bf16x8*)&Vs[srow * AT_LD + sc + 8] = v1v;
    __syncthreads();

    // ---- S^T = K.Q^T per 32-row tile; exp2 directly into A-frag order ----
    bf16x8 pf[4];
#pragma unroll
    for (int kt = 0; kt < 2; ++kt) {
      f32x16 c = {};
#pragma unroll
      for (int dc = 0; dc < 4; ++dc) {
        bf16x8 kf = *(const bf16x8*)&Ks[(kt * 32 + l31) * AT_LD + dc * 16 + half * 8];
        c = MFMA32(kf, qf[dc], c);
      }
#pragma unroll
      for (int kkl = 0; kkl < 2; ++kkl) {
        bf16x8 f;
#pragma unroll
        for (int j = 0; j < 8; ++j) {
          float e = __builtin_amdgcn_exp2f(c[8 * kkl + 4 * (j >> 2) + (j & 3)]);
          lsum += e;
          f[j] = (__bf16)e;
        }
        pf[kt * 2 + kkl] = f;
      }
    }

    // ---- O += P V ----
#pragma unroll
    for (int dt = 0; dt < 2; ++dt)
#pragma unroll
      for (int kk = 0; kk < 4; ++kk) {
        bf16x8 vf = *(const bf16x8*)&Vs[(dt * 32 + l31) * AT_LD + kk * 16 + half * 8];
        o[dt] = MFMA32(pf[kk], vf, o[dt]);
      }
  }

  // ---- denominator: the two halves partition each q's keys ----
  lsum += __shfl_xor(lsum, 32);
  float inv = 1.0f / lsum;  // valid for q == l31

  float iv[16];
#pragma unroll
  for (int r = 0; r < 16; ++r)
    iv[r] = __shfl(inv, (r & 3) + 8 * (r >> 2) + 4 * half);

  // ---- epilogue: O C-layout col=l31=d(+32dt), row=q regmap ----
#pragma unroll
  for (int dt = 0; dt < 2; ++dt)
#pragma unroll
    for (int r = 0; r < 16; ++r) {
      int qr = (r & 3) + 8 * (r >> 2) + 4 * half;
      Out[(size_t)(b * 2048 + q0w + qr) * 1024 + h * 64 + dt * 32 + l31] =
          o[dt][r] * iv[r];
    }
}

// ---------------------------------------------------------------------------
extern "C" void kernel_launch(void* const* d_in, const int* in_sizes, int n_in,
                              void* d_out, int out_size, void* d_ws, size_t ws_size,
                              hipStream_t stream) {
  const float* x = (const float*)d_in[0];        // [4,2048,1024] fp32
  const float* w = (const float*)d_in[1];        // [1024,3072]  fp32
  float* out = (float*)d_out;                    // [4,2048,1024] fp32

  __bf16* Wt = (__bf16*)d_ws;                    // [3072,1024]   6.29 MB
  __bf16* QK = Wt + (size_t)3072 * 1024;         // [8192,2048]  33.55 MB
  __bf16* Xb = QK + (size_t)8192 * 2048;         // [8192,1024]  16.78 MB
  __bf16* Vtr = Xb + (size_t)8192 * 1024;        // [64,64,2048] 16.78 MB

  convert_x<<<8192, 256, 0, stream>>>(x, Xb);
  transpose_w<<<dim3(48, 16), 256, 0, stream>>>(w, Wt);
  gemm_qkv<<<dim3(24, 64), 256, 0, stream>>>(Xb, Wt, QK, Vtr);
  attn<<<dim3(16, 16, 4), 256, 0, stream>>>(QK, Vtr, out);
}